// Round 1
// baseline (492.107 us; speedup 1.0000x reference)
//
#include <hip/hip_runtime.h>
#include <hip/hip_bf16.h>

typedef __bf16 bf16_t;
typedef __bf16 bf16x4 __attribute__((ext_vector_type(4)));
typedef __bf16 bf16x8 __attribute__((ext_vector_type(8)));
typedef float floatx4 __attribute__((ext_vector_type(4)));

#define NB 4
#define NH 12
#define SEQ 2048
#define DM 768

// ---------------------------------------------------------------- cvt f32->bf16
__global__ __launch_bounds__(256) void cvt_kernel(const float* __restrict__ in,
                                                  bf16_t* __restrict__ out) {
  int i = (blockIdx.x * 256 + threadIdx.x) * 4;
  float4 v = *(const float4*)(in + i);
  bf16x4 h;
  h[0] = (bf16_t)v.x; h[1] = (bf16_t)v.y; h[2] = (bf16_t)v.z; h[3] = (bf16_t)v.w;
  *(bf16x4*)(out + i) = h;
}

// ---------------------------------------------- transpose + cvt: in[K][N] -> out[N][K]
__global__ __launch_bounds__(256) void transpose_cvt_kernel(const float* __restrict__ in,
                                                            bf16_t* __restrict__ out,
                                                            int K, int N) {
  __shared__ float tile[32][33];
  int nb = blockIdx.x * 32, kb = blockIdx.y * 32;
  int tx = threadIdx.x & 31, ty = threadIdx.x >> 5;
#pragma unroll
  for (int r = ty; r < 32; r += 8)
    tile[r][tx] = in[(size_t)(kb + r) * N + nb + tx];
  __syncthreads();
#pragma unroll
  for (int r = ty; r < 32; r += 8)
    out[(size_t)(nb + r) * K + kb + tx] = (bf16_t)tile[tx][r];
}

// ---------------------------------------------------------------- QKV GEMM
// A [8192][768] bf16, BT [2304][768] bf16. C = A@BT^T + bias, scattered into
// Q/K/V [B][H][S][64] bf16.  Q pre-scaled by 0.125 (= hd^-0.5).
__global__ __launch_bounds__(256) void gemm_qkv_kernel(
    const bf16_t* __restrict__ A, const bf16_t* __restrict__ BT,
    const float* __restrict__ bias,
    bf16_t* __restrict__ Qo, bf16_t* __restrict__ Ko, bf16_t* __restrict__ Vo) {
  const int K = 768;
  __shared__ __align__(16) bf16_t As[64][40];
  __shared__ __align__(16) bf16_t Bs[64][40];
  int m0 = blockIdx.x * 64, n0 = blockIdx.y * 64;
  int tid = threadIdx.x;
  int wave = tid >> 6, lane = tid & 63, quad = lane >> 4, l16 = lane & 15;
  int sr = tid >> 2, sc = (tid & 3) * 8;
  floatx4 acc[4];
#pragma unroll
  for (int i = 0; i < 4; i++) acc[i] = (floatx4)(0.f);
  for (int k0 = 0; k0 < K; k0 += 32) {
    __syncthreads();
    *(bf16x8*)&As[sr][sc] = *(const bf16x8*)&A[(size_t)(m0 + sr) * K + k0 + sc];
    *(bf16x8*)&Bs[sr][sc] = *(const bf16x8*)&BT[(size_t)(n0 + sr) * K + k0 + sc];
    __syncthreads();
    bf16x8 af = *(const bf16x8*)&As[wave * 16 + l16][quad * 8];
#pragma unroll
    for (int ct = 0; ct < 4; ct++) {
      bf16x8 bf = *(const bf16x8*)&Bs[ct * 16 + l16][quad * 8];
      acc[ct] = __builtin_amdgcn_mfma_f32_16x16x32_bf16(af, bf, acc[ct], 0, 0, 0);
    }
  }
  int which = n0 / 768;  // uniform per block (64 | n0, 64 | 768)
  int rem0 = n0 % 768;
  bf16_t* dst = which == 0 ? Qo : (which == 1 ? Ko : Vo);
  float qscale = which == 0 ? 0.125f : 1.0f;
#pragma unroll
  for (int ct = 0; ct < 4; ct++) {
    int gc = n0 + ct * 16 + l16;
    int rem = rem0 + ct * 16 + l16;
    int h = rem >> 6, hd = rem & 63;
    float bv = bias[gc];
#pragma unroll
    for (int r = 0; r < 4; r++) {
      int gr = m0 + wave * 16 + quad * 4 + r;
      int bb = gr >> 11, s = gr & 2047;
      float val = (acc[ct][r] + bv) * qscale;
      dst[((size_t)((bb * NH + h) * SEQ + s)) * 64 + hd] = (bf16_t)val;
    }
  }
}

// ---------------------------------------------------------------- flash attention
// One block per (b, h, 64 q-rows). 4 waves x 16 q-rows each. K-tiles of 32.
__global__ __launch_bounds__(256) void attn_kernel(
    const bf16_t* __restrict__ Q, const bf16_t* __restrict__ Kg,
    const bf16_t* __restrict__ Vg, bf16_t* __restrict__ Out) {
  __shared__ __align__(16) bf16_t Ks[32][72];     // [key][hd], padded
  __shared__ __align__(16) bf16_t Vt[64][40];     // [hd][key], padded
  __shared__ __align__(16) bf16_t Ps[4][16][40];  // per-wave P  [qrow][key]
  int qb = blockIdx.x * 64;
  int h = blockIdx.y, b = blockIdx.z;
  int tid = threadIdx.x, wave = tid >> 6, lane = tid & 63;
  int quad = lane >> 4, l16 = lane & 15;
  const size_t bh = ((size_t)b * NH + h) * SEQ * 64;
  const bf16_t* Qp = Q + bh;
  const bf16_t* Kp = Kg + bh;
  const bf16_t* Vp = Vg + bh;
  int qrow = qb + wave * 16 + l16;
  bf16x8 qf0 = *(const bf16x8*)&Qp[(size_t)qrow * 64 + quad * 8];
  bf16x8 qf1 = *(const bf16x8*)&Qp[(size_t)qrow * 64 + 32 + quad * 8];
  float m_i[4], l_i[4];
  floatx4 acc_o[4];
#pragma unroll
  for (int r = 0; r < 4; r++) { m_i[r] = -1e30f; l_i[r] = 0.f; }
#pragma unroll
  for (int ot = 0; ot < 4; ot++) acc_o[ot] = (floatx4)(0.f);
  int sr = tid >> 3, sc = (tid & 7) * 8;
  int kt_end = qb / 32 + 2;
  for (int kt = 0; kt < kt_end; kt++) {
    __syncthreads();  // previous iteration's LDS reads done
    int krow = kt * 32 + sr;
    *(bf16x8*)&Ks[sr][sc] = *(const bf16x8*)&Kp[(size_t)krow * 64 + sc];
    bf16x8 vv = *(const bf16x8*)&Vp[(size_t)krow * 64 + sc];
#pragma unroll
    for (int j = 0; j < 8; j++) Vt[sc + j][sr] = vv[j];  // transpose into LDS
    __syncthreads();
    // S = Q @ K^T  (16q x 32k per wave)
    floatx4 s[2];
#pragma unroll
    for (int ct = 0; ct < 2; ct++) {
      bf16x8 kf0 = *(const bf16x8*)&Ks[ct * 16 + l16][quad * 8];
      bf16x8 kf1 = *(const bf16x8*)&Ks[ct * 16 + l16][32 + quad * 8];
      floatx4 z = (floatx4)(0.f);
      z = __builtin_amdgcn_mfma_f32_16x16x32_bf16(qf0, kf0, z, 0, 0, 0);
      z = __builtin_amdgcn_mfma_f32_16x16x32_bf16(qf1, kf1, z, 0, 0, 0);
      s[ct] = z;
    }
    // causal mask
#pragma unroll
    for (int ct = 0; ct < 2; ct++) {
      int key = kt * 32 + ct * 16 + l16;
#pragma unroll
      for (int r = 0; r < 4; r++) {
        int row = qb + wave * 16 + quad * 4 + r;
        if (key > row) s[ct][r] = -1e30f;
      }
    }
    // online softmax (row = quad*4+r lives across the 16 lanes of this quad)
    float alpha[4];
#pragma unroll
    for (int r = 0; r < 4; r++) {
      float mt = fmaxf(s[0][r], s[1][r]);
#pragma unroll
      for (int off = 8; off >= 1; off >>= 1)
        mt = fmaxf(mt, __shfl_xor(mt, off, 16));
      float mnew = fmaxf(m_i[r], mt);
      alpha[r] = __expf(m_i[r] - mnew);
      m_i[r] = mnew;
      float p0 = __expf(s[0][r] - mnew);
      float p1 = __expf(s[1][r] - mnew);
      s[0][r] = p0; s[1][r] = p1;
      float rs = p0 + p1;
#pragma unroll
      for (int off = 8; off >= 1; off >>= 1)
        rs += __shfl_xor(rs, off, 16);
      l_i[r] = l_i[r] * alpha[r] + rs;
    }
#pragma unroll
    for (int ot = 0; ot < 4; ot++)
#pragma unroll
      for (int r = 0; r < 4; r++) acc_o[ot][r] *= alpha[r];
    // P: C-layout -> LDS -> A-layout
#pragma unroll
    for (int ct = 0; ct < 2; ct++)
#pragma unroll
      for (int r = 0; r < 4; r++)
        Ps[wave][quad * 4 + r][ct * 16 + l16] = (bf16_t)s[ct][r];
    __syncthreads();
    bf16x8 pf = *(const bf16x8*)&Ps[wave][l16][quad * 8];
#pragma unroll
    for (int ot = 0; ot < 4; ot++) {
      bf16x8 vf = *(const bf16x8*)&Vt[ot * 16 + l16][quad * 8];
      acc_o[ot] = __builtin_amdgcn_mfma_f32_16x16x32_bf16(pf, vf, acc_o[ot], 0, 0, 0);
    }
  }
  // epilogue: Out[b*S+row][h*64+hd] bf16
#pragma unroll
  for (int ot = 0; ot < 4; ot++) {
#pragma unroll
    for (int r = 0; r < 4; r++) {
      int row = qb + wave * 16 + quad * 4 + r;
      float o = acc_o[ot][r] / l_i[r];
      Out[((size_t)(b * SEQ + row)) * DM + h * 64 + ot * 16 + l16] = (bf16_t)o;
    }
  }
}

// ---------------------------------------------------------------- out-proj GEMM
__global__ __launch_bounds__(256) void gemm_proj_kernel(
    const bf16_t* __restrict__ A, const bf16_t* __restrict__ BT,
    const float* __restrict__ bias, float* __restrict__ out) {
  const int K = 768;
  __shared__ __align__(16) bf16_t As[64][40];
  __shared__ __align__(16) bf16_t Bs[64][40];
  int m0 = blockIdx.x * 64, n0 = blockIdx.y * 64;
  int tid = threadIdx.x;
  int wave = tid >> 6, lane = tid & 63, quad = lane >> 4, l16 = lane & 15;
  int sr = tid >> 2, sc = (tid & 3) * 8;
  floatx4 acc[4];
#pragma unroll
  for (int i = 0; i < 4; i++) acc[i] = (floatx4)(0.f);
  for (int k0 = 0; k0 < K; k0 += 32) {
    __syncthreads();
    *(bf16x8*)&As[sr][sc] = *(const bf16x8*)&A[(size_t)(m0 + sr) * K + k0 + sc];
    *(bf16x8*)&Bs[sr][sc] = *(const bf16x8*)&BT[(size_t)(n0 + sr) * K + k0 + sc];
    __syncthreads();
    bf16x8 af = *(const bf16x8*)&As[wave * 16 + l16][quad * 8];
#pragma unroll
    for (int ct = 0; ct < 4; ct++) {
      bf16x8 bf = *(const bf16x8*)&Bs[ct * 16 + l16][quad * 8];
      acc[ct] = __builtin_amdgcn_mfma_f32_16x16x32_bf16(af, bf, acc[ct], 0, 0, 0);
    }
  }
#pragma unroll
  for (int ct = 0; ct < 4; ct++) {
    int gc = n0 + ct * 16 + l16;
    float bv = bias[gc];
#pragma unroll
    for (int r = 0; r < 4; r++) {
      int gr = m0 + wave * 16 + quad * 4 + r;
      out[(size_t)gr * 768 + gc] = acc[ct][r] + bv;
    }
  }
}

// ---------------------------------------------------------------- launch
extern "C" void kernel_launch(void* const* d_in, const int* in_sizes, int n_in,
                              void* d_out, int out_size, void* d_ws, size_t ws_size,
                              hipStream_t stream) {
  const float* x      = (const float*)d_in[0];
  const float* w_qkv  = (const float*)d_in[1];
  const float* b_qkv  = (const float*)d_in[2];
  const float* w_proj = (const float*)d_in[3];
  const float* b_proj = (const float*)d_in[4];
  float* out = (float*)d_out;
  char* ws = (char*)d_ws;

  // workspace layout (all 16B-aligned)
  bf16_t* xb     = (bf16_t*)(ws + 0);         // 8192*768  bf16 = 12,582,912 B
  bf16_t* wqkvT  = (bf16_t*)(ws + 12582912);  // 2304*768  bf16 =  3,538,944 B
  bf16_t* wprojT = (bf16_t*)(ws + 16121856);  //  768*768  bf16 =  1,179,648 B
  bf16_t* q      = (bf16_t*)(ws + 17301504);  // [4][12][2048][64] bf16
  bf16_t* k      = (bf16_t*)(ws + 29884416);
  bf16_t* v      = (bf16_t*)(ws + 42467328);
  bf16_t* ao     = (bf16_t*)(ws + 55050240);  // [8192][768] bf16
  // total 67,633,152 B

  cvt_kernel<<<6144, 256, 0, stream>>>(x, xb);
  transpose_cvt_kernel<<<dim3(72, 24), 256, 0, stream>>>(w_qkv, wqkvT, 768, 2304);
  transpose_cvt_kernel<<<dim3(24, 24), 256, 0, stream>>>(w_proj, wprojT, 768, 768);
  gemm_qkv_kernel<<<dim3(128, 36), 256, 0, stream>>>(xb, wqkvT, b_qkv, q, k, v);
  attn_kernel<<<dim3(32, 12, 4), 256, 0, stream>>>(q, k, v, ao);
  gemm_proj_kernel<<<dim3(128, 12), 256, 0, stream>>>(ao, wprojT, b_proj, out);
}

// Round 2
// 300.234 us; speedup vs baseline: 1.6391x; 1.6391x over previous
//
#include <hip/hip_runtime.h>
#include <hip/hip_bf16.h>

typedef __bf16 bf16_t;
typedef __bf16 bf16x4 __attribute__((ext_vector_type(4)));
typedef __bf16 bf16x8 __attribute__((ext_vector_type(8)));
typedef float floatx4 __attribute__((ext_vector_type(4)));

#define NB 4
#define NH 12
#define SEQ 2048
#define DM 768
#define LOG2E 1.44269504088896340736f

// ---------------------------------------------------------------- cvt f32->bf16
__global__ __launch_bounds__(256) void cvt_kernel(const float* __restrict__ in,
                                                  bf16_t* __restrict__ out) {
  int i = (blockIdx.x * 256 + threadIdx.x) * 4;
  float4 v = *(const float4*)(in + i);
  bf16x4 h;
  h[0] = (bf16_t)v.x; h[1] = (bf16_t)v.y; h[2] = (bf16_t)v.z; h[3] = (bf16_t)v.w;
  *(bf16x4*)(out + i) = h;
}

// ---------------------------------------------- transpose + cvt: in[K][N] -> out[N][K]
__global__ __launch_bounds__(256) void transpose_cvt_kernel(const float* __restrict__ in,
                                                            bf16_t* __restrict__ out,
                                                            int K, int N) {
  __shared__ float tile[32][33];
  int nb = blockIdx.x * 32, kb = blockIdx.y * 32;
  int tx = threadIdx.x & 31, ty = threadIdx.x >> 5;
#pragma unroll
  for (int r = ty; r < 32; r += 8)
    tile[r][tx] = in[(size_t)(kb + r) * N + nb + tx];
  __syncthreads();
#pragma unroll
  for (int r = ty; r < 32; r += 8)
    out[(size_t)(nb + r) * K + kb + tx] = (bf16_t)tile[tx][r];
}

// ---------------------------------------------------------------- QKV GEMM (unchanged from R1 except Q scale)
// A [8192][768] bf16, BT [2304][768] bf16. C = A@BT^T + bias, scattered into
// Q/K/V [B][H][S][64] bf16.  Q pre-scaled by hd^-0.5 * log2(e)  (exp2-domain softmax).
__global__ __launch_bounds__(256) void gemm_qkv_kernel(
    const bf16_t* __restrict__ A, const bf16_t* __restrict__ BT,
    const float* __restrict__ bias,
    bf16_t* __restrict__ Qo, bf16_t* __restrict__ Ko, bf16_t* __restrict__ Vo) {
  const int K = 768;
  __shared__ __align__(16) bf16_t As[64][40];
  __shared__ __align__(16) bf16_t Bs[64][40];
  int m0 = blockIdx.x * 64, n0 = blockIdx.y * 64;
  int tid = threadIdx.x;
  int wave = tid >> 6, lane = tid & 63, quad = lane >> 4, l16 = lane & 15;
  int sr = tid >> 2, sc = (tid & 3) * 8;
  floatx4 acc[4];
#pragma unroll
  for (int i = 0; i < 4; i++) acc[i] = (floatx4)(0.f);
  for (int k0 = 0; k0 < K; k0 += 32) {
    __syncthreads();
    *(bf16x8*)&As[sr][sc] = *(const bf16x8*)&A[(size_t)(m0 + sr) * K + k0 + sc];
    *(bf16x8*)&Bs[sr][sc] = *(const bf16x8*)&BT[(size_t)(n0 + sr) * K + k0 + sc];
    __syncthreads();
    bf16x8 af = *(const bf16x8*)&As[wave * 16 + l16][quad * 8];
#pragma unroll
    for (int ct = 0; ct < 4; ct++) {
      bf16x8 bf = *(const bf16x8*)&Bs[ct * 16 + l16][quad * 8];
      acc[ct] = __builtin_amdgcn_mfma_f32_16x16x32_bf16(af, bf, acc[ct], 0, 0, 0);
    }
  }
  int which = n0 / 768;  // uniform per block (64 | n0, 64 | 768)
  int rem0 = n0 % 768;
  bf16_t* dst = which == 0 ? Qo : (which == 1 ? Ko : Vo);
  float qscale = which == 0 ? (0.125f * LOG2E) : 1.0f;
#pragma unroll
  for (int ct = 0; ct < 4; ct++) {
    int gc = n0 + ct * 16 + l16;
    int rem = rem0 + ct * 16 + l16;
    int h = rem >> 6, hd = rem & 63;
    float bv = bias[gc];
#pragma unroll
    for (int r = 0; r < 4; r++) {
      int gr = m0 + wave * 16 + quad * 4 + r;
      int bb = gr >> 11, s = gr & 2047;
      float val = (acc[ct][r] + bv) * qscale;
      dst[((size_t)((bb * NH + h) * SEQ + s)) * 64 + hd] = (bf16_t)val;
    }
  }
}

// ---------------------------------------------------------------- V transpose
// V [bh][S][64] -> Vt [bh][64][S]  (so attention PV B-fragments are contiguous)
__global__ __launch_bounds__(256) void vtrans_kernel(const bf16_t* __restrict__ V,
                                                     bf16_t* __restrict__ Vt) {
  __shared__ bf16_t tile[64][66];  // +2 pad: ~2-way on column reads (free)
  int bh = blockIdx.y, s0 = blockIdx.x * 64;
  int tid = threadIdx.x;
  int r = tid >> 4, c4 = (tid & 15) * 4;
  const bf16_t* src = V + (size_t)bh * SEQ * 64;
#pragma unroll
  for (int rr = r; rr < 64; rr += 16)
    *(bf16x4*)&tile[rr][c4] = *(const bf16x4*)&src[(size_t)(s0 + rr) * 64 + c4];
  __syncthreads();
  bf16_t* dst = Vt + (size_t)bh * 64 * SEQ;
#pragma unroll
  for (int hd = r; hd < 64; hd += 16) {
    bf16x4 o;
    o[0] = tile[c4 + 0][hd]; o[1] = tile[c4 + 1][hd];
    o[2] = tile[c4 + 2][hd]; o[3] = tile[c4 + 3][hd];
    *(bf16x4*)&dst[(size_t)hd * SEQ + s0 + c4] = o;
  }
}

// ---------------------------------------------------------------- flash attention, barrier-free
// Grid (48 bh, 16 qt-groups). 4 independent waves/block, 32 q-rows/wave,
// 64-key tiles. K/V fragments straight from global (L2-resident); only LDS
// use is the per-wave P C-layout->A-layout round-trip. NO __syncthreads.
__global__ __launch_bounds__(256) void attn_kernel(
    const bf16_t* __restrict__ Q, const bf16_t* __restrict__ Kg,
    const bf16_t* __restrict__ Vt, bf16_t* __restrict__ Out) {
  __shared__ __align__(16) bf16_t Ps[4][16][68];  // +4 pad: conflict-free quad writes
  const int tid = threadIdx.x;
  const int w = tid >> 6, lane = tid & 63;
  const int quad = lane >> 4, l16 = lane & 15;
  const int bh = blockIdx.x;                     // 0..47
  const int b = bh / NH, h = bh % NH;
  const int qt = (int)(gridDim.y - 1) - (int)blockIdx.y;  // heaviest blocks first
  const int r0 = qt * 128 + w * 32;              // wave's first q-row
  const bf16_t* Qp = Q + (size_t)bh * SEQ * 64;
  const bf16_t* Kp = Kg + (size_t)bh * SEQ * 64;
  const bf16_t* Vp = Vt + (size_t)bh * 64 * SEQ;

  bf16x8 qf[2][2];
#pragma unroll
  for (int rs = 0; rs < 2; rs++)
#pragma unroll
    for (int hh = 0; hh < 2; hh++)
      qf[rs][hh] = *(const bf16x8*)&Qp[(size_t)(r0 + rs * 16 + l16) * 64 + hh * 32 + quad * 8];

  float m_i[2][4], l_i[2][4];
  floatx4 acc[2][4];
#pragma unroll
  for (int rs = 0; rs < 2; rs++)
#pragma unroll
    for (int r = 0; r < 4; r++) { m_i[rs][r] = -1e30f; l_i[rs][r] = 0.f; }
#pragma unroll
  for (int rs = 0; rs < 2; rs++)
#pragma unroll
    for (int ot = 0; ot < 4; ot++) acc[rs][ot] = (floatx4)(0.f);

  const int nt = ((r0 + 31) >> 6) + 1;
  for (int kt = 0; kt < nt; kt++) {
    const int kbase = kt * 64;
    // ---- QK^T: S[32q][64k], fragments direct from global
    bf16x8 kf[4][2];
#pragma unroll
    for (int ct = 0; ct < 4; ct++)
#pragma unroll
      for (int hh = 0; hh < 2; hh++)
        kf[ct][hh] = *(const bf16x8*)&Kp[(size_t)(kbase + ct * 16 + l16) * 64 + hh * 32 + quad * 8];
    floatx4 s[2][4];
#pragma unroll
    for (int rs = 0; rs < 2; rs++)
#pragma unroll
      for (int ct = 0; ct < 4; ct++) {
        floatx4 z = (floatx4)(0.f);
        z = __builtin_amdgcn_mfma_f32_16x16x32_bf16(qf[rs][0], kf[ct][0], z, 0, 0, 0);
        z = __builtin_amdgcn_mfma_f32_16x16x32_bf16(qf[rs][1], kf[ct][1], z, 0, 0, 0);
        s[rs][ct] = z;
      }
    // ---- causal mask (only ever needed on the last tile)
    if (kt == nt - 1) {
#pragma unroll
      for (int rs = 0; rs < 2; rs++)
#pragma unroll
        for (int ct = 0; ct < 4; ct++) {
          int key = kbase + ct * 16 + l16;
#pragma unroll
          for (int r = 0; r < 4; r++) {
            int row = r0 + rs * 16 + quad * 4 + r;
            if (key > row) s[rs][ct][r] = -1e30f;
          }
        }
    }
    // ---- V fragments: issue early so they fly during softmax VALU
    bf16x8 vf[4][2];
#pragma unroll
    for (int ot = 0; ot < 4; ot++)
#pragma unroll
      for (int kh = 0; kh < 2; kh++)
        vf[ot][kh] = *(const bf16x8*)&Vp[(size_t)(ot * 16 + l16) * SEQ + kbase + kh * 32 + quad * 8];
    // ---- online softmax (exp2 domain) + PV, per 16-row set
#pragma unroll
    for (int rs = 0; rs < 2; rs++) {
      float alpha_r[4];
      asm volatile("s_waitcnt lgkmcnt(0)" ::: "memory");  // WAR vs prev pf read
#pragma unroll
      for (int r = 0; r < 4; r++) {
        float mt = fmaxf(fmaxf(s[rs][0][r], s[rs][1][r]), fmaxf(s[rs][2][r], s[rs][3][r]));
#pragma unroll
        for (int off = 8; off >= 1; off >>= 1)
          mt = fmaxf(mt, __shfl_xor(mt, off, 16));
        float mnew = fmaxf(m_i[rs][r], mt);
        float al = __builtin_amdgcn_exp2f(m_i[rs][r] - mnew);
        m_i[rs][r] = mnew;
        float p0 = __builtin_amdgcn_exp2f(s[rs][0][r] - mnew);
        float p1 = __builtin_amdgcn_exp2f(s[rs][1][r] - mnew);
        float p2 = __builtin_amdgcn_exp2f(s[rs][2][r] - mnew);
        float p3 = __builtin_amdgcn_exp2f(s[rs][3][r] - mnew);
        Ps[w][quad * 4 + r][0 * 16 + l16] = (bf16_t)p0;
        Ps[w][quad * 4 + r][1 * 16 + l16] = (bf16_t)p1;
        Ps[w][quad * 4 + r][2 * 16 + l16] = (bf16_t)p2;
        Ps[w][quad * 4 + r][3 * 16 + l16] = (bf16_t)p3;
        float rsum = (p0 + p1) + (p2 + p3);
#pragma unroll
        for (int off = 8; off >= 1; off >>= 1)
          rsum += __shfl_xor(rsum, off, 16);
        l_i[rs][r] = l_i[rs][r] * al + rsum;
        alpha_r[r] = al;
      }
      // rescale O accumulator
#pragma unroll
      for (int ot = 0; ot < 4; ot++)
#pragma unroll
        for (int r = 0; r < 4; r++) acc[rs][ot][r] *= alpha_r[r];
      // P: LDS round-trip to A-layout (per-wave buffer; in-order DS pipe)
      asm volatile("s_waitcnt lgkmcnt(0)" ::: "memory");
      bf16x8 pf0 = *(const bf16x8*)&Ps[w][l16][0 * 32 + quad * 8];
      bf16x8 pf1 = *(const bf16x8*)&Ps[w][l16][1 * 32 + quad * 8];
#pragma unroll
      for (int ot = 0; ot < 4; ot++) {
        acc[rs][ot] = __builtin_amdgcn_mfma_f32_16x16x32_bf16(pf0, vf[ot][0], acc[rs][ot], 0, 0, 0);
        acc[rs][ot] = __builtin_amdgcn_mfma_f32_16x16x32_bf16(pf1, vf[ot][1], acc[rs][ot], 0, 0, 0);
      }
    }
  }
  // ---- epilogue: Out[b*S+row][h*64+hd] bf16
#pragma unroll
  for (int rs = 0; rs < 2; rs++)
#pragma unroll
    for (int ot = 0; ot < 4; ot++)
#pragma unroll
      for (int r = 0; r < 4; r++) {
        int row = r0 + rs * 16 + quad * 4 + r;
        float o = acc[rs][ot][r] / l_i[rs][r];
        Out[((size_t)(b * SEQ + row)) * DM + h * 64 + ot * 16 + l16] = (bf16_t)o;
      }
}

// ---------------------------------------------------------------- out-proj GEMM
__global__ __launch_bounds__(256) void gemm_proj_kernel(
    const bf16_t* __restrict__ A, const bf16_t* __restrict__ BT,
    const float* __restrict__ bias, float* __restrict__ out) {
  const int K = 768;
  __shared__ __align__(16) bf16_t As[64][40];
  __shared__ __align__(16) bf16_t Bs[64][40];
  int m0 = blockIdx.x * 64, n0 = blockIdx.y * 64;
  int tid = threadIdx.x;
  int wave = tid >> 6, lane = tid & 63, quad = lane >> 4, l16 = lane & 15;
  int sr = tid >> 2, sc = (tid & 3) * 8;
  floatx4 acc[4];
#pragma unroll
  for (int i = 0; i < 4; i++) acc[i] = (floatx4)(0.f);
  for (int k0 = 0; k0 < K; k0 += 32) {
    __syncthreads();
    *(bf16x8*)&As[sr][sc] = *(const bf16x8*)&A[(size_t)(m0 + sr) * K + k0 + sc];
    *(bf16x8*)&Bs[sr][sc] = *(const bf16x8*)&BT[(size_t)(n0 + sr) * K + k0 + sc];
    __syncthreads();
    bf16x8 af = *(const bf16x8*)&As[wave * 16 + l16][quad * 8];
#pragma unroll
    for (int ct = 0; ct < 4; ct++) {
      bf16x8 bf = *(const bf16x8*)&Bs[ct * 16 + l16][quad * 8];
      acc[ct] = __builtin_amdgcn_mfma_f32_16x16x32_bf16(af, bf, acc[ct], 0, 0, 0);
    }
  }
#pragma unroll
  for (int ct = 0; ct < 4; ct++) {
    int gc = n0 + ct * 16 + l16;
    float bv = bias[gc];
#pragma unroll
    for (int r = 0; r < 4; r++) {
      int gr = m0 + wave * 16 + quad * 4 + r;
      out[(size_t)gr * 768 + gc] = acc[ct][r] + bv;
    }
  }
}

// ---------------------------------------------------------------- launch
extern "C" void kernel_launch(void* const* d_in, const int* in_sizes, int n_in,
                              void* d_out, int out_size, void* d_ws, size_t ws_size,
                              hipStream_t stream) {
  const float* x      = (const float*)d_in[0];
  const float* w_qkv  = (const float*)d_in[1];
  const float* b_qkv  = (const float*)d_in[2];
  const float* w_proj = (const float*)d_in[3];
  const float* b_proj = (const float*)d_in[4];
  float* out = (float*)d_out;
  char* ws = (char*)d_ws;

  // workspace layout (all 16B-aligned), total 67,633,152 B
  bf16_t* xb     = (bf16_t*)(ws + 0);         // 8192*768  bf16 (dead after gemm_qkv)
  bf16_t* wqkvT  = (bf16_t*)(ws + 12582912);  // 2304*768  bf16
  bf16_t* wprojT = (bf16_t*)(ws + 16121856);  //  768*768  bf16
  bf16_t* q      = (bf16_t*)(ws + 17301504);  // [4][12][2048][64] bf16
  bf16_t* k      = (bf16_t*)(ws + 29884416);
  bf16_t* v      = (bf16_t*)(ws + 42467328);
  bf16_t* ao     = (bf16_t*)(ws + 55050240);  // [8192][768] bf16
  bf16_t* vt     = xb;                        // aliases xb: [4][12][64][2048] bf16

  cvt_kernel<<<6144, 256, 0, stream>>>(x, xb);
  transpose_cvt_kernel<<<dim3(72, 24), 256, 0, stream>>>(w_qkv, wqkvT, 768, 2304);
  transpose_cvt_kernel<<<dim3(24, 24), 256, 0, stream>>>(w_proj, wprojT, 768, 768);
  gemm_qkv_kernel<<<dim3(128, 36), 256, 0, stream>>>(xb, wqkvT, b_qkv, q, k, v);
  vtrans_kernel<<<dim3(32, 48), 256, 0, stream>>>(v, vt);
  attn_kernel<<<dim3(48, 16), 256, 0, stream>>>(q, k, vt, ao);
  gemm_proj_kernel<<<dim3(128, 12), 256, 0, stream>>>(ao, wprojT, b_proj, out);
}